// Round 4
// baseline (1195.922 us; speedup 1.0000x reference)
//
#include <hip/hip_runtime.h>

#define BB 64
#define TT 1024
#define CC 2
#define NN 128

#define REP32(M) M(0)M(1)M(2)M(3)M(4)M(5)M(6)M(7)M(8)M(9)M(10)M(11)M(12)M(13)M(14)M(15)M(16)M(17)M(18)M(19)M(20)M(21)M(22)M(23)M(24)M(25)M(26)M(27)M(28)M(29)M(30)M(31)

// Per-lane E fragments: ea##k = exp(trans[c][4k..4k+3][j0]), eb##k same for j1.
#define E_INIT(k) \
    float4 ea##k, eb##k; \
    ea##k.x = __expf(tr[(4*(k)+0)*NN + j0]); \
    ea##k.y = __expf(tr[(4*(k)+1)*NN + j0]); \
    ea##k.z = __expf(tr[(4*(k)+2)*NN + j0]); \
    ea##k.w = __expf(tr[(4*(k)+3)*NN + j0]); \
    eb##k.x = __expf(tr[(4*(k)+0)*NN + j1]); \
    eb##k.y = __expf(tr[(4*(k)+1)*NN + j1]); \
    eb##k.z = __expf(tr[(4*(k)+2)*NN + j1]); \
    eb##k.w = __expf(tr[(4*(k)+3)*NN + j1]);

// Pin every E component into an ArchVGPR: opaque to remat/sinking, "v" class
// excludes AGPR and scratch unless truly out of registers (we're at ~310/512).
#define E_PIN(k) \
    asm volatile("" : "+v"(ea##k.x), "+v"(ea##k.y), "+v"(ea##k.z), "+v"(ea##k.w)); \
    asm volatile("" : "+v"(eb##k.x), "+v"(eb##k.y), "+v"(eb##k.z), "+v"(eb##k.w));

// 8 MACs per chunk, paired as float2 ops so SLP can form v_pk_fma_f32.
#define MV(k) { const float4 pv = pb[k]; \
    a0.x = fmaf(pv.x, ea##k.x, a0.x); a0.y = fmaf(pv.y, ea##k.y, a0.y); \
    a1.x = fmaf(pv.z, ea##k.z, a1.x); a1.y = fmaf(pv.w, ea##k.w, a1.y); \
    b0.x = fmaf(pv.x, eb##k.x, b0.x); b0.y = fmaf(pv.y, eb##k.y, b0.y); \
    b1.x = fmaf(pv.z, eb##k.z, b1.x); b1.y = fmaf(pv.w, eb##k.w, b1.y); }

// One wave (64 lanes) per (b,c) chain; lane L owns tags j0=L, j1=L+64.
// No __syncthreads anywhere in the scan: wave-lockstep + in-order LDS pipe +
// compiler lgkmcnt ordering make the p round-trip safe with a single buffer
// (the t+1 write's data depends on t's read results, so HW cannot reorder).
// shift = readfirstlane(alpha0): fresh, SGPR-broadcast, no LDS hop.
__global__ __launch_bounds__(64, 1)
void crf_logz_kernel(const float* __restrict__ emissions,
                     const int* __restrict__ lengths,
                     const float* __restrict__ transitions,
                     const float* __restrict__ start_trans,
                     const float* __restrict__ end_trans,
                     float* __restrict__ out)
{
    const int bc = blockIdx.x;
    const int b  = bc >> 1;
    const int c  = bc & 1;
    const int L  = threadIdx.x;        // 0..63
    const int j0 = L;
    const int j1 = L + 64;

    __shared__ float pbuf[NN];         // p = exp(alpha - shift), single buffer

    const float* tr = transitions + c * NN * NN;
    REP32(E_INIT)                      // 256 exp(trans) values
    REP32(E_PIN)                       // ...pinned into ArchVGPRs

    const int len  = lengths[b];       // in [T/2, T]
    const int tmax = len - 1;

    // emissions[b][t][c][*]; t-stride = CC*NN floats
    const float* emisb = emissions + ((size_t)b * TT * CC + c) * NN;

    float alpha0 = start_trans[c * NN + j0] + emisb[j0];
    float alpha1 = start_trans[c * NN + j1] + emisb[j1];

    // 2-deep register emission pipeline (coalesced: lanes contiguous)
    const int t1 = (1 < tmax) ? 1 : tmax, t2 = (2 < tmax) ? 2 : tmax;
    float ecur0 = emisb[(size_t)t1 * (CC * NN) + j0];
    float ecur1 = emisb[(size_t)t1 * (CC * NN) + j1];
    float enx0  = emisb[(size_t)t2 * (CC * NN) + j0];
    float enx1  = emisb[(size_t)t2 * (CC * NN) + j1];

    const float4* pb = (const float4*)pbuf;

    for (int t = 1; t < len; ++t) {
        // prefetch emissions for t+2 (clamped); ~2 steps of latency cover
        const int tp = (t + 2 <= tmax) ? (t + 2) : tmax;
        const float el0 = emisb[(size_t)tp * (CC * NN) + j0];
        const float el1 = emisb[(size_t)tp * (CC * NN) + j1];

        // fresh shift: SGPR broadcast of lane0's alpha0 (tag 0)
        const float shift =
            __int_as_float(__builtin_amdgcn_readfirstlane(__float_as_int(alpha0)));
        pbuf[j0] = __expf(alpha0 - shift);
        pbuf[j1] = __expf(alpha1 - shift);
        __builtin_amdgcn_wave_barrier();   // keep reads below the writes

        float2 a0 = {0.f, 0.f}, a1 = {0.f, 0.f};
        float2 b0 = {0.f, 0.f}, b1 = {0.f, 0.f};
        REP32(MV)                          // 32 broadcast b128 reads + 256 MACs

        alpha0 = shift + __logf((a0.x + a0.y) + (a1.x + a1.y)) + ecur0;
        alpha1 = shift + __logf((b0.x + b0.y) + (b1.x + b1.y)) + ecur1;

        ecur0 = enx0; ecur1 = enx1; enx0 = el0; enx1 = el1;
    }

    // final logsumexp over all 128 tags (2 per lane), pure shuffles
    const float x0 = alpha0 + end_trans[c * NN + j0];
    const float x1 = alpha1 + end_trans[c * NN + j1];
    float m = fmaxf(x0, x1);
    #pragma unroll
    for (int off = 32; off > 0; off >>= 1)
        m = fmaxf(m, __shfl_xor(m, off));
    float s = __expf(x0 - m) + __expf(x1 - m);
    #pragma unroll
    for (int off = 32; off > 0; off >>= 1)
        s += __shfl_xor(s, off);
    if (L == 0) out[b * CC + c] = m + __logf(s);
}

extern "C" void kernel_launch(void* const* d_in, const int* in_sizes, int n_in,
                              void* d_out, int out_size, void* d_ws, size_t ws_size,
                              hipStream_t stream) {
    const float* emissions   = (const float*)d_in[0];
    const int*   lengths     = (const int*)d_in[1];
    const float* transitions = (const float*)d_in[2];
    const float* start_t     = (const float*)d_in[3];
    const float* end_t       = (const float*)d_in[4];
    float* out = (float*)d_out;

    crf_logz_kernel<<<BB * CC, 64, 0, stream>>>(
        emissions, lengths, transitions, start_t, end_t, out);
}

// Round 5
// 541.955 us; speedup vs baseline: 2.2067x; 2.2067x over previous
//
#include <hip/hip_runtime.h>

#define BB 64
#define TT 1024
#define CC 2
#define NN 128

#define REP16(M) M(0)M(1)M(2)M(3)M(4)M(5)M(6)M(7)M(8)M(9)M(10)M(11)M(12)M(13)M(14)M(15)

// fp32 -> bf16 bits, round-to-nearest-even (inputs are never NaN here)
static __device__ __forceinline__ unsigned f2bf(float x) {
    const unsigned u = __float_as_uint(x);
    return (u + 0x7FFFu + ((u >> 16) & 1u)) >> 16;
}
static __device__ __forceinline__ unsigned pk2(float lo, float hi) {
    return f2bf(lo) | (f2bf(hi) << 16);
}

// D.f32 += S0.bf16[0]*S1.bf16[0] + S0.bf16[1]*S1.bf16[1]  (VOP3P, full rate)
#define DOT(acc, pp, ee) \
    asm("v_dot2_f32_bf16 %0, %1, %2, %0" : "+v"(acc) : "v"(pp), "v"(ee));

// Chunk c covers i = 8c..8c+7: 4 packed bf16 pairs of exp(trans[c][i][j]).
#define E_INIT(c) \
    unsigned ue##c##_0 = pk2(__expf(tr[(8*(c)+0)*NN + j]), __expf(tr[(8*(c)+1)*NN + j])); \
    unsigned ue##c##_1 = pk2(__expf(tr[(8*(c)+2)*NN + j]), __expf(tr[(8*(c)+3)*NN + j])); \
    unsigned ue##c##_2 = pk2(__expf(tr[(8*(c)+4)*NN + j]), __expf(tr[(8*(c)+5)*NN + j])); \
    unsigned ue##c##_3 = pk2(__expf(tr[(8*(c)+6)*NN + j]), __expf(tr[(8*(c)+7)*NN + j]));

// Opaque pin: prevents remat/sinking of the packed E registers.
#define E_PIN(c) \
    asm volatile("" : "+v"(ue##c##_0), "+v"(ue##c##_1), "+v"(ue##c##_2), "+v"(ue##c##_3));

// 8 MACs: one b128 broadcast read (4 packed p-pairs) + 4 dot2.
#define MV(c) { const uint4 q = pb[c]; \
    DOT(a0, q.x, ue##c##_0) DOT(a1, q.y, ue##c##_1) \
    DOT(a2, q.z, ue##c##_2) DOT(a3, q.w, ue##c##_3) }

// One workgroup (128 thr = 2 waves) per (b,c) chain; thread j owns tag j and
// the full E column as 64 packed-bf16 VGPRs. amdgpu_waves_per_eu(1,1) caps
// occupancy at 1 wave/EU so the allocator stops spilling E (R2-R4 failure:
// launch_bounds' 2nd arg is only a MIN, allocator still targeted 8 waves/EU).
// One barrier/step: double-buffered bf16 p + stale shift (exact; conditioning
// only, exponents bounded ~e^25 — trivially in bf16/f32 range).
__global__ __launch_bounds__(128, 1) __attribute__((amdgpu_waves_per_eu(1, 1)))
void crf_logz_kernel(const float* __restrict__ emissions,
                     const int* __restrict__ lengths,
                     const float* __restrict__ transitions,
                     const float* __restrict__ start_trans,
                     const float* __restrict__ end_trans,
                     float* __restrict__ out)
{
    const int bc = blockIdx.x;
    const int b  = bc >> 1;
    const int c  = bc & 1;
    const int j  = threadIdx.x;            // 0..127, owns tag j

    __shared__ __align__(16) unsigned short pbufs[2][NN];  // bf16 p, double-buffered
    __shared__ float shbuf[2];             // next-shift broadcast
    __shared__ float red[NN];              // final reduction scratch

    const float* tr = transitions + c * NN * NN;
    REP16(E_INIT)                          // 64 packed regs = 128 bf16 E values
    REP16(E_PIN)

    const int len  = lengths[b];           // in [T/2, T]
    const int tmax = len - 1;

    // emissions[b][t][c][*]; t-stride = CC*NN floats; coalesced per wave
    const float* emisb = emissions + ((size_t)b * TT * CC + c) * NN;

    float alpha = start_trans[c * NN + j] + emisb[j];   // t = 0
    float shift = 0.f;                     // valid first-step shift (|alpha|<~12)

    // 2-deep register emission pipeline
    const int t1 = (1 < tmax) ? 1 : tmax, t2 = (2 < tmax) ? 2 : tmax;
    float ecur = emisb[(size_t)t1 * (CC * NN) + j];
    float enx  = emisb[(size_t)t2 * (CC * NN) + j];

    for (int t = 1; t < len; ++t) {
        // prefetch emission for t+2 (clamped; ~2 steps of latency cover)
        const int tp = (t + 2 <= tmax) ? (t + 2) : tmax;
        const float el = emisb[(size_t)tp * (CC * NN) + j];

        const float p = __expf(alpha - shift);
        pbufs[t & 1][j] = (unsigned short)f2bf(p);
        if (j == 0) shbuf[t & 1] = alpha;
        __syncthreads();                   // single barrier per step
        const float nshift = shbuf[t & 1];

        const uint4* __restrict__ pb = (const uint4*)pbufs[t & 1];
        float a0 = 0.f, a1 = 0.f, a2 = 0.f, a3 = 0.f;
        REP16(MV)                          // 16 b128 broadcasts + 64 dot2

        alpha = shift + __logf((a0 + a1) + (a2 + a3)) + ecur;
        shift = nshift;
        ecur  = enx; enx = el;
    }

    // final logsumexp over tags
    red[j] = alpha + end_trans[c * NN + j];
    __syncthreads();
    if (j < 64) {
        const float x = red[j], y = red[j + 64];
        float m = fmaxf(x, y);
        #pragma unroll
        for (int off = 32; off > 0; off >>= 1)
            m = fmaxf(m, __shfl_xor(m, off));
        float s = __expf(x - m) + __expf(y - m);
        #pragma unroll
        for (int off = 32; off > 0; off >>= 1)
            s += __shfl_xor(s, off);
        if (j == 0) out[b * CC + c] = m + __logf(s);
    }
}

extern "C" void kernel_launch(void* const* d_in, const int* in_sizes, int n_in,
                              void* d_out, int out_size, void* d_ws, size_t ws_size,
                              hipStream_t stream) {
    const float* emissions   = (const float*)d_in[0];
    const int*   lengths     = (const int*)d_in[1];
    const float* transitions = (const float*)d_in[2];
    const float* start_t     = (const float*)d_in[3];
    const float* end_t       = (const float*)d_in[4];
    float* out = (float*)d_out;

    crf_logz_kernel<<<BB * CC, NN, 0, stream>>>(
        emissions, lengths, transitions, start_t, end_t, out);
}